// Round 10
// baseline (402.772 us; speedup 1.0000x reference)
//
#include <hip/hip_runtime.h>

#define S_DIM 512
#define H_DIM 512
#define NH 256
#define TI 8
#define TJ 8

#define AS1 __attribute__((address_space(1)))
#define AS3 __attribute__((address_space(3)))

typedef _Float16 half8 __attribute__((ext_vector_type(8)));
typedef _Float16 half4 __attribute__((ext_vector_type(4)));
typedef float f32x4 __attribute__((ext_vector_type(4)));

__device__ __forceinline__ int swz(int r) { return ((r & 1) << 2) | (r >> 1); }  // perm of 0..7

// ---------------- k0: fused converts ----------------
__global__ __launch_bounds__(256) void convert_all_kernel(const float* __restrict__ feats,
        const float* __restrict__ W1, const float* __restrict__ W2,
        _Float16* __restrict__ f16, _Float16* __restrict__ w1L, _Float16* __restrict__ w2L) {
    int blk = blockIdx.x;
    if (blk < 512) {
        int t = blk * 256 + threadIdx.x;           // 131072 threads, 4 elems each
        float4 v = ((const float4*)feats)[t];
        half4 h;
        h.x = (_Float16)v.x; h.y = (_Float16)v.y; h.z = (_Float16)v.z; h.w = (_Float16)v.w;
        ((half4*)f16)[t] = h;
    } else if (blk < 768) {
        int t = (blk - 512) * 256 + threadIdx.x;   // 65536
        int gcb = t >> 10, n = t & 1023;
        const float* src = (n < H_DIM) ? &W1[(size_t)(gcb * 8) * H_DIM + n]
                                       : &W1[(size_t)(H_DIM + gcb * 8) * H_DIM + (n - H_DIM)];
        half8 v;
#pragma unroll
        for (int j = 0; j < 8; j++) v[j] = (_Float16)src[(size_t)j * H_DIM];
        *(half8*)&w1L[((size_t)gcb * 1024 + n) * 8] = v;
    } else {
        int t = (blk - 768) * 256 + threadIdx.x;   // 16384
        int gcb = t >> 8, n = t & 255;
        half8 v;
#pragma unroll
        for (int j = 0; j < 8; j++) v[j] = (_Float16)W2[(size_t)(gcb * 8 + j) * NH + n];
        *(half8*)&w2L[((size_t)gcb * 256 + n) * 8] = v;
    }
}

// ---------------- k1: prep GEMM  [1024 x 512] @ [512 x 1024] f16 MFMA --------------
__global__ __launch_bounds__(256) void prep_mfma_kernel(const _Float16* __restrict__ f16,
        const _Float16* __restrict__ w1L, const float* __restrict__ b1,
        _Float16* __restrict__ aH, _Float16* __restrict__ cH) {
    const int n0 = blockIdx.x * 64, m0 = blockIdx.y * 64;
    const int tid = threadIdx.x, wave = tid >> 6, lane = tid & 63;
    const int quad = lane >> 4, l16 = lane & 15;
    const int wm = wave >> 1, wn = wave & 1;
    int mrow[2], ncol[2];
#pragma unroll
    for (int mt = 0; mt < 2; mt++) mrow[mt] = m0 + wm * 32 + mt * 16 + l16;
#pragma unroll
    for (int nt = 0; nt < 2; nt++) ncol[nt] = n0 + wn * 32 + nt * 16 + l16;
    f32x4 acc[2][2];
#pragma unroll
    for (int mt = 0; mt < 2; mt++)
#pragma unroll
        for (int nt = 0; nt < 2; nt++) acc[mt][nt] = (f32x4)0.f;
#pragma unroll
    for (int ks = 0; ks < 16; ks++) {
        int gcb = ks * 4 + quad;
        half8 af[2], bf[2];
#pragma unroll
        for (int mt = 0; mt < 2; mt++)
            af[mt] = *(const half8*)&f16[(size_t)mrow[mt] * H_DIM + gcb * 8];
#pragma unroll
        for (int nt = 0; nt < 2; nt++)
            bf[nt] = *(const half8*)&w1L[((size_t)gcb * 1024 + ncol[nt]) * 8];
#pragma unroll
        for (int nt = 0; nt < 2; nt++)
#pragma unroll
            for (int mt = 0; mt < 2; mt++)
                acc[mt][nt] = __builtin_amdgcn_mfma_f32_16x16x32_f16(af[mt], bf[nt],
                                                                     acc[mt][nt], 0, 0, 0);
    }
    const bool first_half = (n0 < H_DIM);
#pragma unroll
    for (int nt = 0; nt < 2; nt++) {
        float bias = first_half ? b1[ncol[nt]] : 0.f;
#pragma unroll
        for (int mt = 0; mt < 2; mt++)
#pragma unroll
            for (int r = 0; r < 4; r++) {
                int m = m0 + wm * 32 + mt * 16 + quad * 4 + r;
                float v = acc[mt][nt][r] + bias;
                if (first_half) aH[(size_t)m * H_DIM + ncol[nt]] = (_Float16)v;
                else            cH[(size_t)m * H_DIM + (ncol[nt] - H_DIM)] = (_Float16)v;
            }
    }
}

// ---------------- k2: pair GEMM, own-frag-in-reg via SLOT-mapped accumulator ----------------
// R5 body with LDS demand cut 7->6 ops/wave/K-step. acc is indexed by SLOT (static):
// slots 0..2 = the three OTHER waves' fragments (LDS reads at wave-uniform offsets
// f(k) = k + (k>=wave)), slot 3 = this wave's own fragment consumed from the register
// it was built in (afc). No conditional register writes, no dynamic register indexing
// (R9's scratch failure mode). Accumulation order per output unchanged -> bit-identical.
// Epilogue maps slot->fragment row via fmap (runtime LDS store address only).
__global__ __launch_bounds__(256, 4) void pair_kernel(
        const _Float16* __restrict__ aH, const _Float16* __restrict__ cH,
        const _Float16* __restrict__ w2L,
        const float* __restrict__ b2, const float* __restrict__ W3,
        const float* __restrict__ b3, float* __restrict__ out) {
    const int jt = blockIdx.x, it = blockIdx.y, b = blockIdx.z;
    const int i0 = it * TI, j0 = jt * TJ;

    __shared__ __align__(16) _Float16 sa[TI * H_DIM];     // 8 KB
    __shared__ __align__(16) _Float16 sc[TJ * H_DIM];     // 8 KB
    __shared__ __align__(16) _Float16 afb[2][2][4][512];  // 16 KB
    __shared__ float spart[4][64];                        // 1 KB

    const int tid = threadIdx.x;
    const int wave = tid >> 6, lane = tid & 63;
    const int quad = lane >> 4, l16 = lane & 15;
    const int nb = wave * 64;

#pragma unroll
    for (int rr0 = 0; rr0 < 2; rr0++) {
        int rr = rr0 * 4 + wave;
        int gc = lane ^ swz(rr & 7);
        __builtin_amdgcn_global_load_lds(
            (const AS1 unsigned int*)&aH[((size_t)(b * S_DIM + i0 + rr)) * H_DIM + gc * 8],
            (AS3 unsigned int*)&sa[rr * H_DIM], 16, 0, 0);
        __builtin_amdgcn_global_load_lds(
            (const AS1 unsigned int*)&cH[((size_t)(b * S_DIM + j0 + rr)) * H_DIM + gc * 8],
            (AS3 unsigned int*)&sc[rr * H_DIM], 16, 0, 0);
    }

    const int hl = l16 >> 3;
    const int ilW = wave * 2 + hl;
    const int saoffW = ilW * H_DIM;
    const int swzAW = swz(ilW);
    const int jl = l16 & 7;
    const int scoff = jl * H_DIM, swzC = swz(jl);

    // slot->fragment map (wave-uniform): f(k) = k + (k >= wave), k=0..2; slot 3 = wave (own)
    const int f0 = (wave == 0) ? 1 : 0;
    const int f1 = (wave <= 1) ? 2 : 1;
    const int f2 = (wave <= 2) ? 3 : 2;
    const int o0 = f0 * 512 + lane * 8;   // element offsets within afb[buf][s]
    const int o1 = f1 * 512 + lane * 8;
    const int o2 = f2 * 512 + lane * 8;

    f32x4 acc[4][4];   // [slot][nt]
#pragma unroll
    for (int k = 0; k < 4; k++)
#pragma unroll
        for (int nt = 0; nt < 4; nt++) acc[k][nt] = (f32x4)0.f;

    const _Float16* bp = &w2L[((size_t)quad * 256 + nb + l16) * 8];

    half8 bnxt[4];
#pragma unroll
    for (int nt = 0; nt < 4; nt++) bnxt[nt] = *(const half8*)&bp[nt * 16 * 8];

    __syncthreads();   // sa/sc staged (drains DMA)

    // prologue: build epoch-0 frags; keep own copies in registers (afc)
    half8 afc[2], afn[2];
#pragma unroll
    for (int s = 0; s < 2; s++) {
        const int gcb = s * 4 + quad;
        half8 va = *(const half8*)&sa[saoffW + ((gcb ^ swzAW) * 8)];
        half8 vc = *(const half8*)&sc[scoff + ((gcb ^ swzC) * 8)];
        half8 af = __builtin_elementwise_max(va + vc, (half8)(_Float16)0.f);
        *(half8*)&afb[0][s][wave][lane * 8] = af;
        afc[s] = af;
    }
    asm volatile("s_waitcnt lgkmcnt(0)" ::: "memory");
    __builtin_amdgcn_s_barrier();
    __builtin_amdgcn_sched_barrier(0);

#pragma unroll
    for (int e = 0; e < 8; e++) {
        const int buf = e & 1;
#pragma unroll
        for (int s = 0; s < 2; s++) {
            const int ks = e * 2 + s;
            half8 bf[4];
#pragma unroll
            for (int nt = 0; nt < 4; nt++) bf[nt] = bnxt[nt];
            if (ks < 15) {
                const _Float16* bn = bp + (size_t)4 * 256 * 8;
#pragma unroll
                for (int nt = 0; nt < 4; nt++) bnxt[nt] = *(const half8*)&bn[nt * 16 * 8];
                bp = bn;
            }
            if (e < 7) {
                const int gcb = (2 * (e + 1) + s) * 4 + quad;
                half8 va = *(const half8*)&sa[saoffW + ((gcb ^ swzAW) * 8)];
                half8 vc = *(const half8*)&sc[scoff + ((gcb ^ swzC) * 8)];
                half8 af = __builtin_elementwise_max(va + vc, (half8)(_Float16)0.f);
                *(half8*)&afb[buf ^ 1][s][wave][lane * 8] = af;
                afn[s] = af;
            }
            // 3 LDS reads (other waves' frags, wave-uniform offsets) + own from register
            const _Float16* fb = &afb[buf][s][0][0];
            half8 am0 = *(const half8*)&fb[o0];
            half8 am1 = *(const half8*)&fb[o1];
            half8 am2 = *(const half8*)&fb[o2];
            half8 am3 = afc[s];
            __builtin_amdgcn_s_setprio(1);
#pragma unroll
            for (int nt = 0; nt < 4; nt++) {
                acc[0][nt] = __builtin_amdgcn_mfma_f32_16x16x32_f16(am0, bf[nt], acc[0][nt], 0, 0, 0);
                acc[1][nt] = __builtin_amdgcn_mfma_f32_16x16x32_f16(am1, bf[nt], acc[1][nt], 0, 0, 0);
                acc[2][nt] = __builtin_amdgcn_mfma_f32_16x16x32_f16(am2, bf[nt], acc[2][nt], 0, 0, 0);
                acc[3][nt] = __builtin_amdgcn_mfma_f32_16x16x32_f16(am3, bf[nt], acc[3][nt], 0, 0, 0);
            }
            __builtin_amdgcn_s_setprio(0);
        }
        if (e < 7) {
            asm volatile("s_waitcnt lgkmcnt(0)" ::: "memory");
            __builtin_amdgcn_s_barrier();
            __builtin_amdgcn_sched_barrier(0);
            afc[0] = afn[0];
            afc[1] = afn[1];
        }
    }

    float b2v[4], w3v[4];
#pragma unroll
    for (int nt = 0; nt < 4; nt++) {
        int n = nb + nt * 16 + l16;
        b2v[nt] = b2[n];
        w3v[nt] = W3[n];
    }
    const int fmap[4] = {f0, f1, f2, wave};   // slot -> fragment (pair-row group)
    float ps[4][4];
#pragma unroll
    for (int k = 0; k < 4; k++)
#pragma unroll
        for (int r = 0; r < 4; r++) {
            float s = 0.f;
#pragma unroll
            for (int nt = 0; nt < 4; nt++) {
                float v = acc[k][nt][r] + b2v[nt];
                v = v > 0.f ? v : 0.f;
                s += v * w3v[nt];
            }
            ps[k][r] = s;
        }
#pragma unroll
    for (int k = 0; k < 4; k++)
#pragma unroll
        for (int r = 0; r < 4; r++) {
            float s = ps[k][r];
            s += __shfl_xor(s, 8, 16);
            s += __shfl_xor(s, 4, 16);
            s += __shfl_xor(s, 2, 16);
            s += __shfl_xor(s, 1, 16);
            ps[k][r] = s;
        }
    if (l16 == 0) {
#pragma unroll
        for (int k = 0; k < 4; k++)
#pragma unroll
            for (int r = 0; r < 4; r++)
                spart[wave][fmap[k] * 16 + quad * 4 + r] = ps[k][r];
    }
    __syncthreads();
    if (tid < 64) {
        float tot = spart[0][tid] + spart[1][tid] + spart[2][tid] + spart[3][tid] + b3[0];
        float sg = 1.f / (1.f + __expf(-tot));
        int i = i0 + (tid >> 3), j = j0 + (tid & 7);
        out[(size_t)b * S_DIM * S_DIM + (size_t)i * S_DIM + j] = sg;
    }
}

extern "C" void kernel_launch(void* const* d_in, const int* in_sizes, int n_in,
                              void* d_out, int out_size, void* d_ws, size_t ws_size,
                              hipStream_t stream) {
    const float* feats = (const float*)d_in[0];
    const float* W1 = (const float*)d_in[1];
    const float* b1 = (const float*)d_in[2];
    const float* W2 = (const float*)d_in[3];
    const float* b2 = (const float*)d_in[4];
    const float* W3 = (const float*)d_in[5];
    const float* b3 = (const float*)d_in[6];
    float* out = (float*)d_out;

    const int B = in_sizes[0] / (S_DIM * H_DIM);   // = 2
    const int M = B * S_DIM;                       // 1024

    char* ws = (char*)d_ws;
    _Float16* f16  = (_Float16*)ws;                 // [1024][512] = 1 MB
    _Float16* aH   = (_Float16*)(ws + (1 << 20));   // [1024][512] = 1 MB
    _Float16* cH   = (_Float16*)(ws + (2 << 20));   // [1024][512] = 1 MB
    _Float16* w1L  = (_Float16*)(ws + (3 << 20));   // 1 MB
    _Float16* w2L  = (_Float16*)(ws + (4 << 20));   // 256 KB

    convert_all_kernel<<<832, 256, 0, stream>>>(feats, W1, W2, f16, w1L, w2L);
    prep_mfma_kernel<<<dim3(16, M / 64), 256, 0, stream>>>(f16, w1L, b1, aH, cH);
    pair_kernel<<<dim3(S_DIM / TJ, S_DIM / TI, B), 256, 0, stream>>>(aH, cH, w2L, b2, W3, b3, out);
}

// Round 11
// 200.908 us; speedup vs baseline: 2.0048x; 2.0048x over previous
//
#include <hip/hip_runtime.h>

#define S_DIM 512
#define H_DIM 512
#define NH 256
#define TI 8
#define TJ 8

#define AS1 __attribute__((address_space(1)))
#define AS3 __attribute__((address_space(3)))

typedef _Float16 half8 __attribute__((ext_vector_type(8)));
typedef _Float16 half4 __attribute__((ext_vector_type(4)));
typedef float f32x4 __attribute__((ext_vector_type(4)));

__device__ __forceinline__ int swz(int r) { return ((r & 1) << 2) | (r >> 1); }  // perm of 0..7

// ---------------- k0: fused converts ----------------
__global__ __launch_bounds__(256) void convert_all_kernel(const float* __restrict__ feats,
        const float* __restrict__ W1, const float* __restrict__ W2,
        _Float16* __restrict__ f16, _Float16* __restrict__ w1L, _Float16* __restrict__ w2L) {
    int blk = blockIdx.x;
    if (blk < 512) {
        int t = blk * 256 + threadIdx.x;           // 131072 threads, 4 elems each
        float4 v = ((const float4*)feats)[t];
        half4 h;
        h.x = (_Float16)v.x; h.y = (_Float16)v.y; h.z = (_Float16)v.z; h.w = (_Float16)v.w;
        ((half4*)f16)[t] = h;
    } else if (blk < 768) {
        int t = (blk - 512) * 256 + threadIdx.x;   // 65536
        int gcb = t >> 10, n = t & 1023;
        const float* src = (n < H_DIM) ? &W1[(size_t)(gcb * 8) * H_DIM + n]
                                       : &W1[(size_t)(H_DIM + gcb * 8) * H_DIM + (n - H_DIM)];
        half8 v;
#pragma unroll
        for (int j = 0; j < 8; j++) v[j] = (_Float16)src[(size_t)j * H_DIM];
        *(half8*)&w1L[((size_t)gcb * 1024 + n) * 8] = v;
    } else {
        int t = (blk - 768) * 256 + threadIdx.x;   // 16384
        int gcb = t >> 8, n = t & 255;
        half8 v;
#pragma unroll
        for (int j = 0; j < 8; j++) v[j] = (_Float16)W2[(size_t)(gcb * 8 + j) * NH + n];
        *(half8*)&w2L[((size_t)gcb * 256 + n) * 8] = v;
    }
}

// ---------------- k1: prep GEMM  [1024 x 512] @ [512 x 1024] f16 MFMA --------------
__global__ __launch_bounds__(256) void prep_mfma_kernel(const _Float16* __restrict__ f16,
        const _Float16* __restrict__ w1L, const float* __restrict__ b1,
        _Float16* __restrict__ aH, _Float16* __restrict__ cH) {
    const int n0 = blockIdx.x * 64, m0 = blockIdx.y * 64;
    const int tid = threadIdx.x, wave = tid >> 6, lane = tid & 63;
    const int quad = lane >> 4, l16 = lane & 15;
    const int wm = wave >> 1, wn = wave & 1;
    int mrow[2], ncol[2];
#pragma unroll
    for (int mt = 0; mt < 2; mt++) mrow[mt] = m0 + wm * 32 + mt * 16 + l16;
#pragma unroll
    for (int nt = 0; nt < 2; nt++) ncol[nt] = n0 + wn * 32 + nt * 16 + l16;
    f32x4 acc[2][2];
#pragma unroll
    for (int mt = 0; mt < 2; mt++)
#pragma unroll
        for (int nt = 0; nt < 2; nt++) acc[mt][nt] = (f32x4)0.f;
#pragma unroll
    for (int ks = 0; ks < 16; ks++) {
        int gcb = ks * 4 + quad;
        half8 af[2], bf[2];
#pragma unroll
        for (int mt = 0; mt < 2; mt++)
            af[mt] = *(const half8*)&f16[(size_t)mrow[mt] * H_DIM + gcb * 8];
#pragma unroll
        for (int nt = 0; nt < 2; nt++)
            bf[nt] = *(const half8*)&w1L[((size_t)gcb * 1024 + ncol[nt]) * 8];
#pragma unroll
        for (int nt = 0; nt < 2; nt++)
#pragma unroll
            for (int mt = 0; mt < 2; mt++)
                acc[mt][nt] = __builtin_amdgcn_mfma_f32_16x16x32_f16(af[mt], bf[nt],
                                                                     acc[mt][nt], 0, 0, 0);
    }
    const bool first_half = (n0 < H_DIM);
#pragma unroll
    for (int nt = 0; nt < 2; nt++) {
        float bias = first_half ? b1[ncol[nt]] : 0.f;
#pragma unroll
        for (int mt = 0; mt < 2; mt++)
#pragma unroll
            for (int r = 0; r < 4; r++) {
                int m = m0 + wm * 32 + mt * 16 + quad * 4 + r;
                float v = acc[mt][nt][r] + bias;
                if (first_half) aH[(size_t)m * H_DIM + ncol[nt]] = (_Float16)v;
                else            cH[(size_t)m * H_DIM + (ncol[nt] - H_DIM)] = (_Float16)v;
            }
    }
}

// ---------------- k2: pair GEMM, 6-LDS-op K-step (own frag in reg), 3 blocks/CU ----------------
// R5 body with LDS demand 7->6 ops/wave/K-step. Slot-mapped acc (R10, correctness-proven):
// slots 0..2 = other waves' frags (LDS, wave-uniform offsets), slot 3 = own frag from the
// register it was built in (afc[2]). launch_bounds(256,3): unified VGPR+AGPR budget 170/wave
// -- the R9/R10 spills were the (256,4) 128-reg cap (64 VGPR + 64 AGPR acc left zero slack).
// Build placement avoids an afn[] double-buffer: next-epoch s0 built BEFORE substep-1's MFMA
// cluster (afc[0] already consumed in substep 0; LDS ops hide under MFMA); next-epoch s1
// issues va/vc READS pre-MFMA, compute+write+afc[1] after (short exposed chain per epoch).
__global__ __launch_bounds__(256, 3) void pair_kernel(
        const _Float16* __restrict__ aH, const _Float16* __restrict__ cH,
        const _Float16* __restrict__ w2L,
        const float* __restrict__ b2, const float* __restrict__ W3,
        const float* __restrict__ b3, float* __restrict__ out) {
    const int jt = blockIdx.x, it = blockIdx.y, b = blockIdx.z;
    const int i0 = it * TI, j0 = jt * TJ;

    __shared__ __align__(16) _Float16 sa[TI * H_DIM];     // 8 KB
    __shared__ __align__(16) _Float16 sc[TJ * H_DIM];     // 8 KB
    __shared__ __align__(16) _Float16 afb[2][2][4][512];  // 16 KB
    __shared__ float spart[4][64];                        // 1 KB

    const int tid = threadIdx.x;
    const int wave = tid >> 6, lane = tid & 63;
    const int quad = lane >> 4, l16 = lane & 15;
    const int nb = wave * 64;

#pragma unroll
    for (int rr0 = 0; rr0 < 2; rr0++) {
        int rr = rr0 * 4 + wave;
        int gc = lane ^ swz(rr & 7);
        __builtin_amdgcn_global_load_lds(
            (const AS1 unsigned int*)&aH[((size_t)(b * S_DIM + i0 + rr)) * H_DIM + gc * 8],
            (AS3 unsigned int*)&sa[rr * H_DIM], 16, 0, 0);
        __builtin_amdgcn_global_load_lds(
            (const AS1 unsigned int*)&cH[((size_t)(b * S_DIM + j0 + rr)) * H_DIM + gc * 8],
            (AS3 unsigned int*)&sc[rr * H_DIM], 16, 0, 0);
    }

    const int hl = l16 >> 3;
    const int ilW = wave * 2 + hl;
    const int saoffW = ilW * H_DIM;
    const int swzAW = swz(ilW);
    const int jl = l16 & 7;
    const int scoff = jl * H_DIM, swzC = swz(jl);

    // slot->fragment map (wave-uniform): f(k) = k + (k >= wave), k=0..2; slot 3 = wave (own)
    const int f0 = (wave == 0) ? 1 : 0;
    const int f1 = (wave <= 1) ? 2 : 1;
    const int f2 = (wave <= 2) ? 3 : 2;
    const int o0 = f0 * 512 + lane * 8;   // element offsets within afb[buf][s]
    const int o1 = f1 * 512 + lane * 8;
    const int o2 = f2 * 512 + lane * 8;

    f32x4 acc[4][4];   // [slot][nt]
#pragma unroll
    for (int k = 0; k < 4; k++)
#pragma unroll
        for (int nt = 0; nt < 4; nt++) acc[k][nt] = (f32x4)0.f;

    const _Float16* bp = &w2L[((size_t)quad * 256 + nb + l16) * 8];

    half8 bnxt[4];
#pragma unroll
    for (int nt = 0; nt < 4; nt++) bnxt[nt] = *(const half8*)&bp[nt * 16 * 8];

    __syncthreads();   // sa/sc staged (drains DMA)

    // prologue: build epoch-0 frags; keep own copies in registers (afc)
    half8 afc[2];
#pragma unroll
    for (int s = 0; s < 2; s++) {
        const int gcb = s * 4 + quad;
        half8 va = *(const half8*)&sa[saoffW + ((gcb ^ swzAW) * 8)];
        half8 vc = *(const half8*)&sc[scoff + ((gcb ^ swzC) * 8)];
        half8 af = __builtin_elementwise_max(va + vc, (half8)(_Float16)0.f);
        *(half8*)&afb[0][s][wave][lane * 8] = af;
        afc[s] = af;
    }
    asm volatile("s_waitcnt lgkmcnt(0)" ::: "memory");
    __builtin_amdgcn_s_barrier();
    __builtin_amdgcn_sched_barrier(0);

#pragma unroll
    for (int e = 0; e < 8; e++) {
        const int buf = e & 1;

        // ---------- substep 0 (ks = 2e) ----------
        {
            half8 bf[4];
#pragma unroll
            for (int nt = 0; nt < 4; nt++) bf[nt] = bnxt[nt];
            {   // ks = 2e <= 14 -> always prefetch
                const _Float16* bn = bp + (size_t)4 * 256 * 8;
#pragma unroll
                for (int nt = 0; nt < 4; nt++) bnxt[nt] = *(const half8*)&bn[nt * 16 * 8];
                bp = bn;
            }
            const _Float16* fb = &afb[buf][0][0][0];
            half8 am0 = *(const half8*)&fb[o0];
            half8 am1 = *(const half8*)&fb[o1];
            half8 am2 = *(const half8*)&fb[o2];
            half8 am3 = afc[0];
            __builtin_amdgcn_s_setprio(1);
#pragma unroll
            for (int nt = 0; nt < 4; nt++) {
                acc[0][nt] = __builtin_amdgcn_mfma_f32_16x16x32_f16(am0, bf[nt], acc[0][nt], 0, 0, 0);
                acc[1][nt] = __builtin_amdgcn_mfma_f32_16x16x32_f16(am1, bf[nt], acc[1][nt], 0, 0, 0);
                acc[2][nt] = __builtin_amdgcn_mfma_f32_16x16x32_f16(am2, bf[nt], acc[2][nt], 0, 0, 0);
                acc[3][nt] = __builtin_amdgcn_mfma_f32_16x16x32_f16(am3, bf[nt], acc[3][nt], 0, 0, 0);
            }
            __builtin_amdgcn_s_setprio(0);
        }

        // ---------- substep 1 (ks = 2e+1) ----------
        {
            half8 bf[4];
#pragma unroll
            for (int nt = 0; nt < 4; nt++) bf[nt] = bnxt[nt];
            if (e < 7) {   // ks = 2e+1 < 15
                const _Float16* bn = bp + (size_t)4 * 256 * 8;
#pragma unroll
                for (int nt = 0; nt < 4; nt++) bnxt[nt] = *(const half8*)&bn[nt * 16 * 8];
                bp = bn;
            }
            const _Float16* fb = &afb[buf][1][0][0];
            half8 am0 = *(const half8*)&fb[o0];
            half8 am1 = *(const half8*)&fb[o1];
            half8 am2 = *(const half8*)&fb[o2];
            half8 am3 = afc[1];

            half8 va1, vc1;
            if (e < 7) {
                // build next-epoch s0 NOW (afc[0] already consumed in substep 0);
                // hides under this substep's MFMA cluster
                const int gcb0 = (2 * (e + 1) + 0) * 4 + quad;
                half8 va0 = *(const half8*)&sa[saoffW + ((gcb0 ^ swzAW) * 8)];
                half8 vc0 = *(const half8*)&sc[scoff + ((gcb0 ^ swzC) * 8)];
                half8 af0 = __builtin_elementwise_max(va0 + vc0, (half8)(_Float16)0.f);
                *(half8*)&afb[buf ^ 1][0][wave][lane * 8] = af0;
                afc[0] = af0;
                // issue next-epoch s1 READS (complete during MFMAs; computed after)
                const int gcb1 = (2 * (e + 1) + 1) * 4 + quad;
                va1 = *(const half8*)&sa[saoffW + ((gcb1 ^ swzAW) * 8)];
                vc1 = *(const half8*)&sc[scoff + ((gcb1 ^ swzC) * 8)];
            }
            __builtin_amdgcn_s_setprio(1);
#pragma unroll
            for (int nt = 0; nt < 4; nt++) {
                acc[0][nt] = __builtin_amdgcn_mfma_f32_16x16x32_f16(am0, bf[nt], acc[0][nt], 0, 0, 0);
                acc[1][nt] = __builtin_amdgcn_mfma_f32_16x16x32_f16(am1, bf[nt], acc[1][nt], 0, 0, 0);
                acc[2][nt] = __builtin_amdgcn_mfma_f32_16x16x32_f16(am2, bf[nt], acc[2][nt], 0, 0, 0);
                acc[3][nt] = __builtin_amdgcn_mfma_f32_16x16x32_f16(am3, bf[nt], acc[3][nt], 0, 0, 0);
            }
            __builtin_amdgcn_s_setprio(0);
            if (e < 7) {
                half8 af1 = __builtin_elementwise_max(va1 + vc1, (half8)(_Float16)0.f);
                *(half8*)&afb[buf ^ 1][1][wave][lane * 8] = af1;
                afc[1] = af1;
            }
        }

        if (e < 7) {
            asm volatile("s_waitcnt lgkmcnt(0)" ::: "memory");
            __builtin_amdgcn_s_barrier();
            __builtin_amdgcn_sched_barrier(0);
        }
    }

    float b2v[4], w3v[4];
#pragma unroll
    for (int nt = 0; nt < 4; nt++) {
        int n = nb + nt * 16 + l16;
        b2v[nt] = b2[n];
        w3v[nt] = W3[n];
    }
    const int fmap[4] = {f0, f1, f2, wave};   // slot -> fragment (pair-row group)
    float ps[4][4];
#pragma unroll
    for (int k = 0; k < 4; k++)
#pragma unroll
        for (int r = 0; r < 4; r++) {
            float s = 0.f;
#pragma unroll
            for (int nt = 0; nt < 4; nt++) {
                float v = acc[k][nt][r] + b2v[nt];
                v = v > 0.f ? v : 0.f;
                s += v * w3v[nt];
            }
            ps[k][r] = s;
        }
#pragma unroll
    for (int k = 0; k < 4; k++)
#pragma unroll
        for (int r = 0; r < 4; r++) {
            float s = ps[k][r];
            s += __shfl_xor(s, 8, 16);
            s += __shfl_xor(s, 4, 16);
            s += __shfl_xor(s, 2, 16);
            s += __shfl_xor(s, 1, 16);
            ps[k][r] = s;
        }
    if (l16 == 0) {
#pragma unroll
        for (int k = 0; k < 4; k++)
#pragma unroll
            for (int r = 0; r < 4; r++)
                spart[wave][fmap[k] * 16 + quad * 4 + r] = ps[k][r];
    }
    __syncthreads();
    if (tid < 64) {
        float tot = spart[0][tid] + spart[1][tid] + spart[2][tid] + spart[3][tid] + b3[0];
        float sg = 1.f / (1.f + __expf(-tot));
        int i = i0 + (tid >> 3), j = j0 + (tid & 7);
        out[(size_t)b * S_DIM * S_DIM + (size_t)i * S_DIM + j] = sg;
    }
}

extern "C" void kernel_launch(void* const* d_in, const int* in_sizes, int n_in,
                              void* d_out, int out_size, void* d_ws, size_t ws_size,
                              hipStream_t stream) {
    const float* feats = (const float*)d_in[0];
    const float* W1 = (const float*)d_in[1];
    const float* b1 = (const float*)d_in[2];
    const float* W2 = (const float*)d_in[3];
    const float* b2 = (const float*)d_in[4];
    const float* W3 = (const float*)d_in[5];
    const float* b3 = (const float*)d_in[6];
    float* out = (float*)d_out;

    const int B = in_sizes[0] / (S_DIM * H_DIM);   // = 2
    const int M = B * S_DIM;                       // 1024

    char* ws = (char*)d_ws;
    _Float16* f16  = (_Float16*)ws;                 // [1024][512] = 1 MB
    _Float16* aH   = (_Float16*)(ws + (1 << 20));   // [1024][512] = 1 MB
    _Float16* cH   = (_Float16*)(ws + (2 << 20));   // [1024][512] = 1 MB
    _Float16* w1L  = (_Float16*)(ws + (3 << 20));   // 1 MB
    _Float16* w2L  = (_Float16*)(ws + (4 << 20));   // 256 KB

    convert_all_kernel<<<832, 256, 0, stream>>>(feats, W1, W2, f16, w1L, w2L);
    prep_mfma_kernel<<<dim3(16, M / 64), 256, 0, stream>>>(f16, w1L, b1, aH, cH);
    pair_kernel<<<dim3(S_DIM / TJ, S_DIM / TI, B), 256, 0, stream>>>(aH, cH, w2L, b2, W3, b3, out);
}